// Round 1
// baseline (4178.529 us; speedup 1.0000x reference)
//
#include <hip/hip_runtime.h>
#include <hip/hip_bf16.h>

#define N_NODES 100000
#define N_TYPE  50000

// ---------------- small weight prep: M0 = fc0_w^T @ W1, M1 = fc1_w^T @ W1, cb = fc_b @ W1 ----
__global__ __launch_bounds__(256) void prep_small_kernel(
    const float* __restrict__ fc0_w, const float* __restrict__ fc1_w,
    const float* __restrict__ fc0_b, const float* __restrict__ fc1_b,
    const float* __restrict__ W1,
    float* __restrict__ M0, float* __restrict__ M1, float* __restrict__ cb) {
  int idx = blockIdx.x * 256 + threadIdx.x;
  if (idx < 128 * 128) {
    int i = idx >> 7, j = idx & 127;
    float s = 0.f;
    #pragma unroll 4
    for (int o = 0; o < 128; ++o) s = fmaf(fc0_w[o * 128 + i], W1[o * 128 + j], s);
    M0[idx] = s;
  } else if (idx < 128 * 128 + 256 * 128) {
    int r = idx - 128 * 128;
    int i = r >> 7, j = r & 127;
    float s = 0.f;
    #pragma unroll 4
    for (int o = 0; o < 128; ++o) s = fmaf(fc1_w[o * 256 + i], W1[o * 128 + j], s);
    M1[r] = s;
  } else if (idx < 128 * 128 + 256 * 128 + 256) {
    int r = idx - (128 * 128 + 256 * 128);
    int t = r >> 7, j = r & 127;
    const float* bb = t ? fc1_b : fc0_b;
    float s = 0.f;
    for (int o = 0; o < 128; ++o) s = fmaf(bb[o], W1[o * 128 + j], s);
    cb[r] = s;
  }
}

// ---------------- tiled fp32 GEMM: C[M][NC] = act(A[M][KTOT]) @ B[KTOT][NC] (+bc) ------------
// act = relu(a + bk[k]) when RELU_BIAS, else identity.
template <int NC, int KTOT, bool RELU_BIAS>
__global__ __launch_bounds__(256) void sgemm_kernel(
    const float* __restrict__ A, const float* __restrict__ B,
    const float* __restrict__ bk, const float* __restrict__ bc,
    float* __restrict__ C, int M) {
  constexpr int BM = 64, KC = 64;
  constexpr int COLG = NC / 4;        // float4 col groups per row of C tile
  constexpr int ROWG = 256 / COLG;    // row groups
  constexpr int RPT  = BM / ROWG;     // rows per thread
  __shared__ float As[BM][KC];        // row-major, stride 64 (aligned float4 rows)
  __shared__ float Bs[KC][NC];

  const int tid = threadIdx.x;
  const int row0 = blockIdx.x * BM;
  const int tx = tid % COLG, ty = tid / COLG;

  float acc[RPT][4];
  #pragma unroll
  for (int i = 0; i < RPT; ++i)
    for (int j = 0; j < 4; ++j) acc[i][j] = 0.f;

  for (int kc = 0; kc < KTOT; kc += KC) {
    // stage A tile (coalesced float4 rows)
    {
      const int c4 = tid & 15;   // 16 float4 per 64-wide k chunk
      const int r0 = tid >> 4;   // 16 rows per pass
      #pragma unroll
      for (int p = 0; p < 4; ++p) {
        int r = r0 + p * 16;
        int gr = row0 + r; if (gr > M - 1) gr = M - 1;
        float4 v = *(const float4*)(A + (size_t)gr * KTOT + kc + c4 * 4);
        if (RELU_BIAS) {
          const float4 bb = *(const float4*)(bk + kc + c4 * 4);
          v.x = fmaxf(v.x + bb.x, 0.f);
          v.y = fmaxf(v.y + bb.y, 0.f);
          v.z = fmaxf(v.z + bb.z, 0.f);
          v.w = fmaxf(v.w + bb.w, 0.f);
        }
        *(float4*)&As[r][c4 * 4] = v;
      }
    }
    // stage B tile
    {
      constexpr int NF4 = KC * NC / 4;
      #pragma unroll
      for (int it = 0; it < NF4 / 256; ++it) {
        int i = it * 256 + tid;
        int k = i / (NC / 4), c4 = i % (NC / 4);
        *(float4*)&Bs[k][c4 * 4] =
            *(const float4*)(B + (size_t)(kc + k) * NC + c4 * 4);
      }
    }
    __syncthreads();
    #pragma unroll 4
    for (int kk = 0; kk < KC; ++kk) {
      float a[RPT];
      #pragma unroll
      for (int i = 0; i < RPT; ++i) a[i] = As[ty * RPT + i][kk];
      const float4 b = *(const float4*)&Bs[kk][tx * 4];
      #pragma unroll
      for (int i = 0; i < RPT; ++i) {
        acc[i][0] = fmaf(a[i], b.x, acc[i][0]);
        acc[i][1] = fmaf(a[i], b.y, acc[i][1]);
        acc[i][2] = fmaf(a[i], b.z, acc[i][2]);
        acc[i][3] = fmaf(a[i], b.w, acc[i][3]);
      }
    }
    __syncthreads();
  }
  float4 cbv = make_float4(0.f, 0.f, 0.f, 0.f);
  if (bc) cbv = *(const float4*)(bc + tx * 4);
  #pragma unroll
  for (int i = 0; i < RPT; ++i) {
    int gr = row0 + ty * RPT + i;
    if (gr < M) {
      float4 r;
      r.x = acc[i][0] + cbv.x;
      r.y = acc[i][1] + cbv.y;
      r.z = acc[i][2] + cbv.z;
      r.w = acc[i][3] + cbv.w;
      *(float4*)(C + (size_t)gr * NC + tx * 4) = r;
    }
  }
}

// ---------------- SpMM scatter-add: out[row] += w * feat[col], F features ---------------------
__global__ __launch_bounds__(256) void spmm_kernel_128(
    const float* __restrict__ feat, const int* __restrict__ erow,
    const int* __restrict__ ecol, const float* __restrict__ ew,
    float* __restrict__ out, int nE) {
  const int tid = threadIdx.x;
  const int eg = tid >> 5;        // 8 edges per block, 32 lanes each
  const int lane = tid & 31;
  const int e = blockIdx.x * 8 + eg;
  if (e >= nE) return;
  const int r = erow[e];
  const int c = ecol[e];
  const float w = ew[e];
  const float4 v = *(const float4*)(feat + (size_t)c * 128 + lane * 4);
  float* dst = out + (size_t)r * 128 + lane * 4;
  atomicAdd(dst + 0, v.x * w);
  atomicAdd(dst + 1, v.y * w);
  atomicAdd(dst + 2, v.z * w);
  atomicAdd(dst + 3, v.w * w);
}

__global__ __launch_bounds__(256) void spmm_kernel_64(
    const float* __restrict__ feat, const int* __restrict__ erow,
    const int* __restrict__ ecol, const float* __restrict__ ew,
    float* __restrict__ out, int nE) {
  const int tid = threadIdx.x;
  const int eg = tid >> 4;        // 16 edges per block, 16 lanes each
  const int lane = tid & 15;
  const int e = blockIdx.x * 16 + eg;
  if (e >= nE) return;
  const int r = erow[e];
  const int c = ecol[e];
  const float w = ew[e];
  const float4 v = *(const float4*)(feat + (size_t)c * 64 + lane * 4);
  float* dst = out + (size_t)r * 64 + lane * 4;
  atomicAdd(dst + 0, v.x * w);
  atomicAdd(dst + 1, v.y * w);
  atomicAdd(dst + 2, v.z * w);
  atomicAdd(dst + 3, v.w * w);
}

// ---------------- head: out = relu(s2 + b2) @ pred_w^T + pred_b ------------------------------
__global__ __launch_bounds__(256) void final_kernel(
    const float* __restrict__ s2, const float* __restrict__ pred_w,
    const float* __restrict__ pred_b, const float* __restrict__ b2,
    float* __restrict__ out, int M) {
  __shared__ float pw[512];
  __shared__ float pb[8];
  __shared__ float bb[64];
  const int tid = threadIdx.x;
  for (int i = tid; i < 512; i += 256) pw[i] = pred_w[i];
  if (tid < 8) pb[tid] = pred_b[tid];
  if (tid < 64) bb[tid] = b2[tid];
  __syncthreads();
  const int node = blockIdx.x * 32 + (tid >> 3);
  const int c = tid & 7;
  if (node >= M) return;
  const float* row = s2 + (size_t)node * 64;
  float acc = pb[c];
  #pragma unroll 8
  for (int k = 0; k < 64; ++k)
    acc = fmaf(fmaxf(row[k] + bb[k], 0.f), pw[c * 64 + k], acc);
  out[node * 8 + c] = acc;
}

// ---------------- zero fill ------------------------------------------------------------------
__global__ void zero_kernel(float4* __restrict__ p, int n4) {
  int i = blockIdx.x * blockDim.x + threadIdx.x;
  const int stride = gridDim.x * blockDim.x;
  for (; i < n4; i += stride) p[i] = make_float4(0.f, 0.f, 0.f, 0.f);
}

extern "C" void kernel_launch(void* const* d_in, const int* in_sizes, int n_in,
                              void* d_out, int out_size, void* d_ws, size_t ws_size,
                              hipStream_t stream) {
  const float* feat0  = (const float*)d_in[0];
  const float* feat1  = (const float*)d_in[1];
  const float* fc0_w  = (const float*)d_in[2];
  const float* fc0_b  = (const float*)d_in[3];
  const float* fc1_w  = (const float*)d_in[4];
  const float* fc1_b  = (const float*)d_in[5];
  const float* W1     = (const float*)d_in[6];
  const float* b1     = (const float*)d_in[7];
  const float* W2     = (const float*)d_in[8];
  const float* b2     = (const float*)d_in[9];
  const float* pred_w = (const float*)d_in[10];
  const float* pred_b = (const float*)d_in[11];
  const int*   erow   = (const int*)d_in[12];
  const int*   ecol   = (const int*)d_in[13];
  const float* ew     = (const float*)d_in[14];
  float* out = (float*)d_out;
  const int nE = in_sizes[12];

  char* ws = (char*)d_ws;
  float* M0 = (float*)ws;                                   // 64 KiB
  float* M1 = (float*)(ws + 65536);                         // 128 KiB
  float* cb = (float*)(ws + 65536 + 131072);                // 1 KiB
  float* bufA = (float*)(ws + 262144);                      // h1 [100k][128] -> h2 [100k][64]
  float* bufB = (float*)(ws + 262144 + (size_t)N_NODES * 128 * 4);  // s1 -> s2
  float* h1 = bufA;
  float* s1 = bufB;
  float* h2 = bufA;
  float* s2 = bufB;

  hipLaunchKernelGGL(prep_small_kernel, dim3(194), dim3(256), 0, stream,
                     fc0_w, fc1_w, fc0_b, fc1_b, W1, M0, M1, cb);
  // h1[:50000] = feat0 @ M0 + cb0
  hipLaunchKernelGGL((sgemm_kernel<128, 128, false>), dim3((N_TYPE + 63) / 64), dim3(256), 0,
                     stream, feat0, M0, nullptr, cb, h1, N_TYPE);
  // h1[50000:] = feat1 @ M1 + cb1
  hipLaunchKernelGGL((sgemm_kernel<128, 256, false>), dim3((N_TYPE + 63) / 64), dim3(256), 0,
                     stream, feat1, M1, nullptr, cb + 128, h1 + (size_t)N_TYPE * 128, N_TYPE);
  // s1 = adj @ h1
  hipLaunchKernelGGL(zero_kernel, dim3(2048), dim3(256), 0, stream,
                     (float4*)s1, N_NODES * 128 / 4);
  hipLaunchKernelGGL(spmm_kernel_128, dim3((nE + 7) / 8), dim3(256), 0, stream,
                     h1, erow, ecol, ew, s1, nE);
  // h2 = relu(s1 + b1) @ W2
  hipLaunchKernelGGL((sgemm_kernel<64, 128, true>), dim3((N_NODES + 63) / 64), dim3(256), 0,
                     stream, s1, W2, b1, nullptr, h2, N_NODES);
  // s2 = adj @ h2
  hipLaunchKernelGGL(zero_kernel, dim3(2048), dim3(256), 0, stream,
                     (float4*)s2, N_NODES * 64 / 4);
  hipLaunchKernelGGL(spmm_kernel_64, dim3((nE + 15) / 16), dim3(256), 0, stream,
                     h2, erow, ecol, ew, s2, nE);
  // out = relu(s2 + b2) @ pred_w^T + pred_b
  hipLaunchKernelGGL(final_kernel, dim3((N_NODES + 31) / 32), dim3(256), 0, stream,
                     s2, pred_w, pred_b, b2, out, N_NODES);
}

// Round 2
// 549.334 us; speedup vs baseline: 7.6065x; 7.6065x over previous
//
#include <hip/hip_runtime.h>
#include <hip/hip_bf16.h>

#define N_NODES 100000
#define N_TYPE  50000
#define SCAN_E  1024   // elements per scan block (256 thr x 4)

// ---------------- small weight prep: M0 = fc0_w^T @ W1, M1 = fc1_w^T @ W1, cb = fc_b @ W1 ----
__global__ __launch_bounds__(256) void prep_small_kernel(
    const float* __restrict__ fc0_w, const float* __restrict__ fc1_w,
    const float* __restrict__ fc0_b, const float* __restrict__ fc1_b,
    const float* __restrict__ W1,
    float* __restrict__ M0, float* __restrict__ M1, float* __restrict__ cb) {
  int idx = blockIdx.x * 256 + threadIdx.x;
  if (idx < 128 * 128) {
    int i = idx >> 7, j = idx & 127;
    float s = 0.f;
    #pragma unroll 4
    for (int o = 0; o < 128; ++o) s = fmaf(fc0_w[o * 128 + i], W1[o * 128 + j], s);
    M0[idx] = s;
  } else if (idx < 128 * 128 + 256 * 128) {
    int r = idx - 128 * 128;
    int i = r >> 7, j = r & 127;
    float s = 0.f;
    #pragma unroll 4
    for (int o = 0; o < 128; ++o) s = fmaf(fc1_w[o * 256 + i], W1[o * 128 + j], s);
    M1[r] = s;
  } else if (idx < 128 * 128 + 256 * 128 + 256) {
    int r = idx - (128 * 128 + 256 * 128);
    int t = r >> 7, j = r & 127;
    const float* bb = t ? fc1_b : fc0_b;
    float s = 0.f;
    for (int o = 0; o < 128; ++o) s = fmaf(bb[o], W1[o * 128 + j], s);
    cb[r] = s;
  }
}

// ---------------- tiled fp32 GEMM: C[M][NC] = act(A[M][KTOT]) @ B[KTOT][NC] (+bc) ------------
template <int NC, int KTOT, bool RELU_BIAS>
__global__ __launch_bounds__(256) void sgemm_kernel(
    const float* __restrict__ A, const float* __restrict__ B,
    const float* __restrict__ bk, const float* __restrict__ bc,
    float* __restrict__ C, int M) {
  constexpr int BM = 64, KC = 64;
  constexpr int COLG = NC / 4;
  constexpr int ROWG = 256 / COLG;
  constexpr int RPT  = BM / ROWG;
  __shared__ float As[BM][KC];
  __shared__ float Bs[KC][NC];

  const int tid = threadIdx.x;
  const int row0 = blockIdx.x * BM;
  const int tx = tid % COLG, ty = tid / COLG;

  float acc[RPT][4];
  #pragma unroll
  for (int i = 0; i < RPT; ++i)
    for (int j = 0; j < 4; ++j) acc[i][j] = 0.f;

  for (int kc = 0; kc < KTOT; kc += KC) {
    {
      const int c4 = tid & 15;
      const int r0 = tid >> 4;
      #pragma unroll
      for (int p = 0; p < 4; ++p) {
        int r = r0 + p * 16;
        int gr = row0 + r; if (gr > M - 1) gr = M - 1;
        float4 v = *(const float4*)(A + (size_t)gr * KTOT + kc + c4 * 4);
        if (RELU_BIAS) {
          const float4 bb = *(const float4*)(bk + kc + c4 * 4);
          v.x = fmaxf(v.x + bb.x, 0.f);
          v.y = fmaxf(v.y + bb.y, 0.f);
          v.z = fmaxf(v.z + bb.z, 0.f);
          v.w = fmaxf(v.w + bb.w, 0.f);
        }
        *(float4*)&As[r][c4 * 4] = v;
      }
    }
    {
      constexpr int NF4 = KC * NC / 4;
      #pragma unroll
      for (int it = 0; it < NF4 / 256; ++it) {
        int i = it * 256 + tid;
        int k = i / (NC / 4), c4 = i % (NC / 4);
        *(float4*)&Bs[k][c4 * 4] =
            *(const float4*)(B + (size_t)(kc + k) * NC + c4 * 4);
      }
    }
    __syncthreads();
    #pragma unroll 4
    for (int kk = 0; kk < KC; ++kk) {
      float a[RPT];
      #pragma unroll
      for (int i = 0; i < RPT; ++i) a[i] = As[ty * RPT + i][kk];
      const float4 b = *(const float4*)&Bs[kk][tx * 4];
      #pragma unroll
      for (int i = 0; i < RPT; ++i) {
        acc[i][0] = fmaf(a[i], b.x, acc[i][0]);
        acc[i][1] = fmaf(a[i], b.y, acc[i][1]);
        acc[i][2] = fmaf(a[i], b.z, acc[i][2]);
        acc[i][3] = fmaf(a[i], b.w, acc[i][3]);
      }
    }
    __syncthreads();
  }
  float4 cbv = make_float4(0.f, 0.f, 0.f, 0.f);
  if (bc) cbv = *(const float4*)(bc + tx * 4);
  #pragma unroll
  for (int i = 0; i < RPT; ++i) {
    int gr = row0 + ty * RPT + i;
    if (gr < M) {
      float4 r;
      r.x = acc[i][0] + cbv.x;
      r.y = acc[i][1] + cbv.y;
      r.z = acc[i][2] + cbv.z;
      r.w = acc[i][3] + cbv.w;
      *(float4*)(C + (size_t)gr * NC + tx * 4) = r;
    }
  }
}

// ---------------- CSR build ------------------------------------------------------------------
__global__ __launch_bounds__(256) void hist_kernel(
    const int* __restrict__ erow, int* __restrict__ counts, int nE) {
  int e = blockIdx.x * 256 + threadIdx.x;
  if (e < nE) atomicAdd(&counts[erow[e]], 1);
}

// per-block exclusive scan over 1024-elt chunks; writes per-elt exclusive + block total
__global__ __launch_bounds__(256) void scan1_kernel(
    const int* __restrict__ counts, int* __restrict__ excl,
    int* __restrict__ bsum, int n) {
  __shared__ int lds[256];
  const int t = threadIdx.x;
  const int base = blockIdx.x * SCAN_E + t * 4;
  int4 v = make_int4(0, 0, 0, 0);
  if (base + 3 < n) v = *(const int4*)(counts + base);
  else {
    if (base + 0 < n) v.x = counts[base + 0];
    if (base + 1 < n) v.y = counts[base + 1];
    if (base + 2 < n) v.z = counts[base + 2];
    if (base + 3 < n) v.w = counts[base + 3];
  }
  const int lsum = v.x + v.y + v.z + v.w;
  lds[t] = lsum;
  __syncthreads();
  #pragma unroll
  for (int off = 1; off < 256; off <<= 1) {
    int y = (t >= off) ? lds[t - off] : 0;
    __syncthreads();
    lds[t] += y;
    __syncthreads();
  }
  const int excl_t = lds[t] - lsum;
  if (t == 255) bsum[blockIdx.x] = lds[255];
  int e0 = excl_t, e1 = e0 + v.x, e2 = e1 + v.y, e3 = e2 + v.z;
  if (base + 3 < n) {
    *(int4*)(excl + base) = make_int4(e0, e1, e2, e3);
  } else {
    if (base + 0 < n) excl[base + 0] = e0;
    if (base + 1 < n) excl[base + 1] = e1;
    if (base + 2 < n) excl[base + 2] = e2;
    if (base + 3 < n) excl[base + 3] = e3;
  }
}

__global__ __launch_bounds__(256) void scan2_kernel(
    int* __restrict__ bsum, int* __restrict__ boff, int nb) {
  __shared__ int lds[256];
  const int t = threadIdx.x;
  int v = (t < nb) ? bsum[t] : 0;
  lds[t] = v;
  __syncthreads();
  #pragma unroll
  for (int off = 1; off < 256; off <<= 1) {
    int y = (t >= off) ? lds[t - off] : 0;
    __syncthreads();
    lds[t] += y;
    __syncthreads();
  }
  if (t < nb) boff[t] = lds[t] - v;  // exclusive
}

__global__ __launch_bounds__(256) void scan3_kernel(
    const int* __restrict__ excl, const int* __restrict__ boff,
    int* __restrict__ row_start, int* __restrict__ cursor, int n, int nE) {
  int i = blockIdx.x * 256 + threadIdx.x;
  if (i < n) {
    int rs = excl[i] + boff[i >> 10];
    row_start[i] = rs;
    cursor[i] = rs;
  } else if (i == n) {
    row_start[n] = nE;
  }
}

__global__ __launch_bounds__(256) void scatter_kernel(
    const int* __restrict__ erow, const int* __restrict__ ecol,
    const float* __restrict__ ew, int* __restrict__ cursor,
    float2* __restrict__ spack, int nE) {
  int e = blockIdx.x * 256 + threadIdx.x;
  if (e >= nE) return;
  int r = erow[e];
  int pos = atomicAdd(&cursor[r], 1);
  spack[pos] = make_float2(__int_as_float(ecol[e]), ew[e]);
}

// ---------------- CSR SpMM: wave per row, register accumulate, no atomics --------------------
__global__ __launch_bounds__(256) void spmm_csr128(
    const float* __restrict__ feat, const int* __restrict__ row_start,
    const float2* __restrict__ spack, float* __restrict__ out, int M) {
  const int wid = (blockIdx.x * 256 + threadIdx.x) >> 6;
  const int lane = threadIdx.x & 63;
  if (wid >= M) return;
  const int s = row_start[wid], e = row_start[wid + 1];
  float2 acc = make_float2(0.f, 0.f);
  int j = s;
  for (; j + 1 < e; j += 2) {
    const float2 p0 = spack[j];
    const float2 p1 = spack[j + 1];
    const float2 v0 = *(const float2*)(feat + (size_t)__float_as_int(p0.x) * 128 + lane * 2);
    const float2 v1 = *(const float2*)(feat + (size_t)__float_as_int(p1.x) * 128 + lane * 2);
    acc.x = fmaf(v0.x, p0.y, acc.x);
    acc.y = fmaf(v0.y, p0.y, acc.y);
    acc.x = fmaf(v1.x, p1.y, acc.x);
    acc.y = fmaf(v1.y, p1.y, acc.y);
  }
  if (j < e) {
    const float2 p0 = spack[j];
    const float2 v0 = *(const float2*)(feat + (size_t)__float_as_int(p0.x) * 128 + lane * 2);
    acc.x = fmaf(v0.x, p0.y, acc.x);
    acc.y = fmaf(v0.y, p0.y, acc.y);
  }
  *(float2*)(out + (size_t)wid * 128 + lane * 2) = acc;
}

__global__ __launch_bounds__(256) void spmm_csr64(
    const float* __restrict__ feat, const int* __restrict__ row_start,
    const float2* __restrict__ spack, float* __restrict__ out, int M) {
  const int wid = (blockIdx.x * 256 + threadIdx.x) >> 6;
  const int lane = threadIdx.x & 63;
  if (wid >= M) return;
  const int s = row_start[wid], e = row_start[wid + 1];
  float acc = 0.f;
  int j = s;
  for (; j + 1 < e; j += 2) {
    const float2 p0 = spack[j];
    const float2 p1 = spack[j + 1];
    const float v0 = feat[(size_t)__float_as_int(p0.x) * 64 + lane];
    const float v1 = feat[(size_t)__float_as_int(p1.x) * 64 + lane];
    acc = fmaf(v0, p0.y, acc);
    acc = fmaf(v1, p1.y, acc);
  }
  if (j < e) {
    const float2 p0 = spack[j];
    acc = fmaf(feat[(size_t)__float_as_int(p0.x) * 64 + lane], p0.y, acc);
  }
  out[(size_t)wid * 64 + lane] = acc;
}

// ---------------- head: out = relu(s2 + b2) @ pred_w^T + pred_b ------------------------------
__global__ __launch_bounds__(256) void final_kernel(
    const float* __restrict__ s2, const float* __restrict__ pred_w,
    const float* __restrict__ pred_b, const float* __restrict__ b2,
    float* __restrict__ out, int M) {
  __shared__ float pw[512];
  __shared__ float pb[8];
  __shared__ float bb[64];
  const int tid = threadIdx.x;
  for (int i = tid; i < 512; i += 256) pw[i] = pred_w[i];
  if (tid < 8) pb[tid] = pred_b[tid];
  if (tid < 64) bb[tid] = b2[tid];
  __syncthreads();
  const int node = blockIdx.x * 32 + (tid >> 3);
  const int c = tid & 7;
  if (node >= M) return;
  const float* row = s2 + (size_t)node * 64;
  float acc = pb[c];
  #pragma unroll 8
  for (int k = 0; k < 64; ++k)
    acc = fmaf(fmaxf(row[k] + bb[k], 0.f), pw[c * 64 + k], acc);
  out[node * 8 + c] = acc;
}

// ---------------- zero fill ------------------------------------------------------------------
__global__ void zero_kernel(float4* __restrict__ p, int n4) {
  int i = blockIdx.x * blockDim.x + threadIdx.x;
  const int stride = gridDim.x * blockDim.x;
  for (; i < n4; i += stride) p[i] = make_float4(0.f, 0.f, 0.f, 0.f);
}

extern "C" void kernel_launch(void* const* d_in, const int* in_sizes, int n_in,
                              void* d_out, int out_size, void* d_ws, size_t ws_size,
                              hipStream_t stream) {
  const float* feat0  = (const float*)d_in[0];
  const float* feat1  = (const float*)d_in[1];
  const float* fc0_w  = (const float*)d_in[2];
  const float* fc0_b  = (const float*)d_in[3];
  const float* fc1_w  = (const float*)d_in[4];
  const float* fc1_b  = (const float*)d_in[5];
  const float* W1     = (const float*)d_in[6];
  const float* b1     = (const float*)d_in[7];
  const float* W2     = (const float*)d_in[8];
  const float* b2     = (const float*)d_in[9];
  const float* pred_w = (const float*)d_in[10];
  const float* pred_b = (const float*)d_in[11];
  const int*   erow   = (const int*)d_in[12];
  const int*   ecol   = (const int*)d_in[13];
  const float* ew     = (const float*)d_in[14];
  float* out = (float*)d_out;
  const int nE = in_sizes[12];
  const int N = N_NODES;

  char* ws = (char*)d_ws;
  size_t off = 0;
  float* M0 = (float*)(ws + off); off += 64 * 1024;
  float* M1 = (float*)(ws + off); off += 128 * 1024;
  float* cb = (float*)(ws + off); off += 4 * 1024;
  int* counts    = (int*)(ws + off); off += 512 * 1024;   // N ints
  int* excl      = (int*)(ws + off); off += 512 * 1024;   // N ints
  int* row_start = (int*)(ws + off); off += 512 * 1024;   // N+1 ints
  int* cursor    = (int*)(ws + off); off += 512 * 1024;   // N ints
  int* bsum      = (int*)(ws + off); off += 2 * 1024;
  int* boff      = (int*)(ws + off); off += 2 * 1024;
  float2* spack  = (float2*)(ws + off); off += (size_t)nE * 8;  // 12.8 MB
  float* bufA = (float*)(ws + off); off += (size_t)N * 128 * 4; // 51.2 MB
  float* bufB = (float*)(ws + off); off += (size_t)N * 128 * 4; // 51.2 MB
  float* h1 = bufA;
  float* s1 = bufB;
  float* h2 = bufA;
  float* s2 = bufB;

  const int nb1 = (N + SCAN_E - 1) / SCAN_E;  // 98

  // ---- CSR build ----
  hipLaunchKernelGGL(zero_kernel, dim3(128), dim3(256), 0, stream,
                     (float4*)counts, N / 4);
  hipLaunchKernelGGL(hist_kernel, dim3((nE + 255) / 256), dim3(256), 0, stream,
                     erow, counts, nE);
  hipLaunchKernelGGL(scan1_kernel, dim3(nb1), dim3(256), 0, stream,
                     counts, excl, bsum, N);
  hipLaunchKernelGGL(scan2_kernel, dim3(1), dim3(256), 0, stream, bsum, boff, nb1);
  hipLaunchKernelGGL(scan3_kernel, dim3((N + 256) / 256), dim3(256), 0, stream,
                     excl, boff, row_start, cursor, N, nE);
  hipLaunchKernelGGL(scatter_kernel, dim3((nE + 255) / 256), dim3(256), 0, stream,
                     erow, ecol, ew, cursor, spack, nE);

  // ---- dense pipeline ----
  hipLaunchKernelGGL(prep_small_kernel, dim3(194), dim3(256), 0, stream,
                     fc0_w, fc1_w, fc0_b, fc1_b, W1, M0, M1, cb);
  hipLaunchKernelGGL((sgemm_kernel<128, 128, false>), dim3((N_TYPE + 63) / 64), dim3(256), 0,
                     stream, feat0, M0, nullptr, cb, h1, N_TYPE);
  hipLaunchKernelGGL((sgemm_kernel<128, 256, false>), dim3((N_TYPE + 63) / 64), dim3(256), 0,
                     stream, feat1, M1, nullptr, cb + 128, h1 + (size_t)N_TYPE * 128, N_TYPE);
  // s1 = adj @ h1
  hipLaunchKernelGGL(spmm_csr128, dim3((N * 64 + 255) / 256), dim3(256), 0, stream,
                     h1, row_start, spack, s1, N);
  // h2 = relu(s1 + b1) @ W2
  hipLaunchKernelGGL((sgemm_kernel<64, 128, true>), dim3((N + 63) / 64), dim3(256), 0,
                     stream, s1, W2, b1, nullptr, h2, N);
  // s2 = adj @ h2
  hipLaunchKernelGGL(spmm_csr64, dim3((N * 64 + 255) / 256), dim3(256), 0, stream,
                     h2, row_start, spack, s2, N);
  // head
  hipLaunchKernelGGL(final_kernel, dim3((N + 31) / 32), dim3(256), 0, stream,
                     s2, pred_w, pred_b, b2, out, N);
}